// Round 6
// baseline (89.497 us; speedup 1.0000x reference)
//
#include <hip/hip_runtime.h>

#define N_ANCH 49104
#define NB_IMG 16
#define NGT 100
#define NC 80
#define BPI 96                 // blocks per image
#define APB 512                // anchors (rows) per block
#define NBLK (BPI * NB_IMG)    // 1536
#define OFF_B NBLK
#define OFF_P (2 * NBLK)
#define ROW_F4 (NC / 4)        // 20 float4 per row
#define BLK_F4 (APB * ROW_F4)  // 10240 float4 per block
#define WCHUNK (BLK_F4 / 4)    // 2560 float4 per wave

#define LOG2E 1.4426950408889634f
#define LN2   0.6931471805599453f
#define FSCALE (0.75f * LN2)

__device__ __forceinline__ float frcp(float x){ return __builtin_amdgcn_rcpf(x); }
__device__ __forceinline__ float fexp2(float x){ return __builtin_amdgcn_exp2f(x); }
__device__ __forceinline__ float flog2(float x){ return __builtin_amdgcn_logf(x); }

// p(x)^2 * softplus(x)/LN2  (caller scales by 0.75*LN2)
__device__ __forceinline__ float f0_term(float x){
  float xl = x * LOG2E;
  float mx = fmaxf(xl, 0.f);
  float mn = fminf(xl, 0.f);
  float u  = fexp2(mn - mx);      // e^{-|x|}
  float w  = 1.0f + u;
  float lw = flog2(w);
  float g  = mn - lw;             // log2(sigmoid)
  return fexp2(g + g) * (lw + mx);
}

// (f1 - f0) correction for the one-hot label class (absolute units)
__device__ __forceinline__ float corr_term(float x){
  float xl = x * LOG2E;
  float mx = fmaxf(xl, 0.f);
  float mn = fminf(xl, 0.f);
  float u  = fexp2(mn - mx);
  float w  = 1.0f + u;
  float lw = flog2(w);
  float p2   = fexp2(2.f * (mn - lw));
  float omp2 = fexp2(-2.f * (mx + lw));
  float sp   = LN2 * (lw + mx);
  float spn  = LN2 * (lw - mn);
  return 0.25f * omp2 * spn - 0.75f * p2 * sp;
}

// anchor geometry for global anchor index a (f64 matches numpy gen)
__device__ __forceinline__ void anchor_geom(int a, float& x1, float& y1,
                                            float& x2, float& y2){
  int f, lg, st, rel;
  if      (a < 36864){ f = 64; lg = 6; st = 8;   rel = a; }
  else if (a < 46080){ f = 32; lg = 5; st = 16;  rel = a - 36864; }
  else if (a < 48384){ f = 16; lg = 4; st = 32;  rel = a - 46080; }
  else if (a < 48960){ f = 8;  lg = 3; st = 64;  rel = a - 48384; }
  else               { f = 4;  lg = 2; st = 128; rel = a - 48960; }
  int cell = rel / 9;
  int k    = rel - cell * 9;
  int yy   = cell >> lg;
  int xx   = cell & (f - 1);
  int rr = (k >= 6) ? 2 : ((k >= 3) ? 1 : 0);
  int sc = k - rr * 3;
  double sq  = (rr == 0) ? 0.7071067811865476 : ((rr == 1) ? 1.0 : 1.4142135623730951);
  double scl = (sc == 0) ? 4.0 : ((sc == 1) ? 5.039684199579493 : 6.349604207872798);
  double ss  = (double)st * scl;
  double wd  = ss / sq, hd = ss * sq;
  double cxd = ((double)xx + 0.5) * (double)st;
  double cyd = ((double)yy + 0.5) * (double)st;
  x1 = (float)(cxd - wd * 0.5);
  y1 = (float)(cyd - hd * 0.5);
  x2 = (float)(cxd + wd * 0.5);
  y2 = (float)(cyd + hd * 0.5);
}

__global__ __launch_bounds__(256, 6) void fused_loss_kernel(
    const float* __restrict__ cls,
    const float* __restrict__ bbox,
    const float* __restrict__ gtb,
    const int*   __restrict__ gtl,
    const unsigned char* __restrict__ gmask,
    float* __restrict__ ws)
{
  const int tid = threadIdx.x;
  const int wv = tid >> 6, ln = tid & 63;
  const int b  = blockIdx.y;
  const int a0 = blockIdx.x * APB;
  const int bid = b * BPI + blockIdx.x;
  const int nvalid = min(N_ANCH - a0, APB);
  const int nf4 = nvalid * ROW_F4;

  __shared__ float4 s_cgt[NGT + 4];
  __shared__ float  s_carea[NGT + 4];
  __shared__ int    s_clab[NGT + 4];
  __shared__ float  s_w[APB];          // 1 = pos|neg (counted), 0 = ignored
  __shared__ int    s_lab[APB];        // pos label or -1
  __shared__ float  s_r0[4], s_r1[4], s_r2[4];

  const float* clsbase = cls + (size_t)(b * N_ANCH + a0) * NC;
  const float4* cp = (const float4*)clsbase;

  float accB = 0.f, posf = 0.f;
  float s0 = 0.f, s1 = 0.f, s2 = 0.f, s3 = 0.f;

  if (wv == 3){
    // ================= ASSIGNMENT WAVE =================
    // 1) block y-extent over all 512 anchors (8 per lane)
    float ymin = 3.0e38f, ymax = -3.0e38f;
    #pragma unroll
    for (int r = 0; r < 8; ++r){
      int a = a0 + r * 64 + ln;
      if (a < N_ANCH){
        float x1, y1, x2, y2;
        anchor_geom(a, x1, y1, x2, y2);
        ymin = fminf(ymin, y1);
        ymax = fmaxf(ymax, y2);
      }
    }
    #pragma unroll
    for (int o = 1; o < 64; o <<= 1){
      ymin = fminf(ymin, __shfl_xor(ymin, o));
      ymax = fmaxf(ymax, __shfl_xor(ymax, o));
    }

    // 2) mask layout detection (bool8 vs int32 vs float32)
    const unsigned int* mw = (const unsigned int*)gmask;
    bool nf = false, ob = false;
    for (int i = ln; i < (NB_IMG * NGT) / 4; i += 64){
      unsigned int w = mw[i];
      nf |= (w != 0u && w != 0x3F800000u);
      ob |= ((w & 0xFFFFFF00u) != 0u);
    }
    bool byteLayout = __any((int)nf) && __any((int)ob);

    // 3) GT staging with y-prefilter + order-preserving compaction
    const float4* g4 = (const float4*)gtb;
    float4 g = g4[b * NGT + ln];
    int v = byteLayout ? (gmask[b * NGT + ln] != 0)
                       : (((const unsigned int*)gmask)[b * NGT + ln] != 0u);
    bool pass = v && (g.y < ymax) && (g.w > ymin);   // exact: fails => IoU == 0
    unsigned long long bal = __ballot(pass);
    int pre = __popcll(bal & ((1ull << ln) - 1ull));
    if (pass){
      s_cgt[pre] = g;
      s_carea[pre] = (g.z - g.x) * (g.w - g.y);
      s_clab[pre] = gtl[b * NGT + ln];
    }
    int c0 = __popcll(bal);
    bool pass1 = false; float4 g1;
    if (ln < NGT - 64){
      g1 = g4[b * NGT + 64 + ln];
      int v1 = byteLayout ? (gmask[b * NGT + 64 + ln] != 0)
                          : (((const unsigned int*)gmask)[b * NGT + 64 + ln] != 0u);
      pass1 = v1 && (g1.y < ymax) && (g1.w > ymin);
    }
    unsigned long long bal1 = __ballot(pass1);
    int pre1 = c0 + __popcll(bal1 & ((1ull << ln) - 1ull));
    if (pass1){
      s_cgt[pre1] = g1;
      s_carea[pre1] = (g1.z - g1.x) * (g1.w - g1.y);
      s_clab[pre1] = gtl[b * NGT + 64 + ln];
    }
    int cnt = c0 + __popcll(bal1);
    if (ln == 0){
      float4 far4; far4.x = 3e9f; far4.y = 3e9f; far4.z = 3e9f; far4.w = 3e9f;
      s_cgt[cnt] = far4;     s_carea[cnt] = 0.f;     s_clab[cnt] = 0;
      s_cgt[cnt + 1] = far4; s_carea[cnt + 1] = 0.f; s_clab[cnt + 1] = 0;
    }
    const int cntp = (cnt + 1) & ~1;   // even, >= 2

    // 4) IoU argmax + SmoothL1 for all 512 anchors (8 per lane)
    #pragma unroll 2
    for (int r = 0; r < 8; ++r){
      int row = r * 64 + ln;
      int a = a0 + row;
      float x1, y1, x2, y2;
      anchor_geom(min(a, N_ANCH - 1), x1, y1, x2, y2);
      float areaA = (x2 - x1) * (y2 - y1);
      float best_iou = -1.f; int best = 0;
      for (int j = 0; j < cntp; j += 2){
        #pragma unroll
        for (int u2 = 0; u2 < 2; ++u2){
          int jj = j + u2;
          float4 gg = s_cgt[jj];
          float lx = fmaxf(x1, gg.x), ly = fmaxf(y1, gg.y);
          float rx = fminf(x2, gg.z), ry = fminf(y2, gg.w);
          float iw = fmaxf(rx - lx, 0.f), ih = fmaxf(ry - ly, 0.f);
          float I  = iw * ih;
          float U  = (areaA + s_carea[jj]) - I;
          float iou = I * frcp(U);
          best = (iou > best_iou) ? jj : best;
          best_iou = fmaxf(iou, best_iou);
        }
      }
      bool va  = a < N_ANCH;
      bool pos = va && (best_iou >= 0.5f);
      bool ign = va && !pos && (best_iou >= 0.4f);
      s_w[row]   = ign ? 0.f : 1.f;
      s_lab[row] = pos ? s_clab[best] : -1;

      if (pos){
        posf += 1.f;
        float4 gg = s_cgt[best];
        float aw = x2 - x1, ah = y2 - y1;
        float axc = (x1 + x2) * 0.5f, ayc = (y1 + y2) * 0.5f;
        float gw = fmaxf(gg.z - gg.x, 1e-6f), gh = fmaxf(gg.w - gg.y, 1e-6f);
        float gxc = (gg.x + gg.z) * 0.5f, gyc = (gg.y + gg.w) * 0.5f;
        float t0 = (gxc - axc) / aw, t1 = (gyc - ayc) / ah;
        float t2 = LN2 * flog2(gw * frcp(aw));
        float t3 = LN2 * flog2(gh * frcp(ah));
        float4 bp = ((const float4*)bbox)[(size_t)b * N_ANCH + a];
        const float BETA = 1.0f / 9.0f;
        float d0 = fabsf(bp.x - t0), d1 = fabsf(bp.y - t1);
        float d2 = fabsf(bp.z - t2), d3 = fabsf(bp.w - t3);
        accB += (d0 < BETA) ? 4.5f * d0 * d0 : d0 - 0.5f * BETA;
        accB += (d1 < BETA) ? 4.5f * d1 * d1 : d1 - 0.5f * BETA;
        accB += (d2 < BETA) ? 4.5f * d2 * d2 : d2 - 0.5f * BETA;
        accB += (d3 < BETA) ? 4.5f * d3 * d3 : d3 - 0.5f * BETA;
      }
    }
  }

  // ================= UNWEIGHTED f0 STREAM =================
  // waves 0-2 start at cycle 0; wave 3 streams its quarter after assignment
  {
    const int iend = min(nf4, (wv + 1) * WCHUNK);
    #pragma unroll 2
    for (int i = wv * WCHUNK + ln; i < iend; i += 64){
      float4 c4 = cp[i];
      s0 += f0_term(c4.x);
      s1 += f0_term(c4.y);
      s2 += f0_term(c4.z);
      s3 += f0_term(c4.w);
    }
  }
  __syncthreads();

  // ================= CORRECTIONS (all waves) =================
  float fsub = 0.f, fcorr = 0.f;
  #pragma unroll
  for (int h = 0; h < 2; ++h){
    int row = wv * 128 + h * 64 + ln;
    if (row < nvalid){
      int lab = s_lab[row];
      if (lab >= 0) fcorr += corr_term(clsbase[row * NC + lab]);  // L2 hit
      if (s_w[row] == 0.f){
        const float4* rp = cp + row * ROW_F4;
        float t0 = 0.f, t1 = 0.f, t2 = 0.f, t3 = 0.f;
        #pragma unroll 5
        for (int k2 = 0; k2 < ROW_F4; ++k2){
          float4 c4 = rp[k2];                                     // L2 hit
          t0 += f0_term(c4.x); t1 += f0_term(c4.y);
          t2 += f0_term(c4.z); t3 += f0_term(c4.w);
        }
        fsub += (t0 + t1) + (t2 + t3);
      }
    }
  }
  float accC = fmaf(FSCALE, ((s0 + s1) + (s2 + s3)) - fsub, fcorr);

  // ================= block reduction =================
  #pragma unroll
  for (int o = 32; o > 0; o >>= 1){
    accC += __shfl_down(accC, o);
    accB += __shfl_down(accB, o);
    posf += __shfl_down(posf, o);
  }
  if (ln == 0){ s_r0[wv] = accC; s_r1[wv] = accB; s_r2[wv] = posf; }
  __syncthreads();
  if (tid == 0){
    ws[bid]         = s_r0[0] + s_r0[1] + s_r0[2] + s_r0[3];
    ws[OFF_B + bid] = s_r1[0] + s_r1[1] + s_r1[2] + s_r1[3];
    ws[OFF_P + bid] = s_r2[0] + s_r2[1] + s_r2[2] + s_r2[3];
  }
}

__global__ void finalize_kernel(const float* __restrict__ ws,
                                float* __restrict__ out)
{
  __shared__ float sC[NB_IMG], sB[NB_IMG];
  const int tid = threadIdx.x;          // 512 threads = 8 waves
  const int wv = tid >> 6, ln = tid & 63;
  #pragma unroll
  for (int i = 0; i < 2; ++i){
    int b = wv * 2 + i;
    float c = 0.f, bb = 0.f, p = 0.f;
    for (int k = ln; k < BPI; k += 64){
      c  += ws[b * BPI + k];
      bb += ws[OFF_B + b * BPI + k];
      p  += ws[OFF_P + b * BPI + k];
    }
    #pragma unroll
    for (int o = 32; o > 0; o >>= 1){
      c += __shfl_down(c, o); bb += __shfl_down(bb, o); p += __shfl_down(p, o);
    }
    if (ln == 0){
      float tot = fmaxf(p, 1.f);
      sC[b] = c / tot;
      sB[b] = bb / tot;
    }
  }
  __syncthreads();
  if (tid == 0){
    float lc = 0.f, lb = 0.f;
    #pragma unroll
    for (int b = 0; b < NB_IMG; ++b){ lc += sC[b]; lb += sB[b]; }
    out[0] = lc / 16.f;
    out[1] = 10.f * lb / 16.f;
  }
}

extern "C" void kernel_launch(void* const* d_in, const int* in_sizes, int n_in,
                              void* d_out, int out_size, void* d_ws, size_t ws_size,
                              hipStream_t stream) {
  const float* cls  = (const float*)d_in[0];
  const float* bbox = (const float*)d_in[1];
  const float* gtb  = (const float*)d_in[2];
  const int*   gtl  = (const int*)d_in[3];
  const unsigned char* gmask = (const unsigned char*)d_in[4];

  float* ws = (float*)d_ws;   // 3*NBLK floats, fully overwritten every call

  dim3 grid(BPI, NB_IMG);
  fused_loss_kernel<<<grid, 256, 0, stream>>>(cls, bbox, gtb, gtl, gmask, ws);
  finalize_kernel<<<1, 512, 0, stream>>>(ws, (float*)d_out);
}

// Round 7
// 72.450 us; speedup vs baseline: 1.2353x; 1.2353x over previous
//
#include <hip/hip_runtime.h>

#define N_ANCH 49104
#define NB_IMG 16
#define NGT 100
#define NC 80
#define BPI 96                 // blocks per image
#define APB 512                // anchors (rows) per block
#define NBLK (BPI * NB_IMG)    // 1536
#define OFF_B NBLK
#define OFF_P (2 * NBLK)
#define ROW_F4 (NC / 4)        // 20 float4 per row

#define LOG2E 1.4426950408889634f
#define LN2   0.6931471805599453f
#define FSCALE (0.75f * LN2)

// compile-time f64 anchor half-extents: W2 = st*scale/sqrt(ratio)*0.5 (exact
// same op order as numpy), H2 = st*scale*sqrt(ratio)*0.5. k = rr*3+sc.
#define SC0 4.0
#define SC1 5.039684199579493
#define SC2 6.349604207872798
#define RQ0 0.7071067811865476
#define RQ1 1.0
#define RQ2 1.4142135623730951
#define WH(st,R,S) (double)(st)*(S)/(R)*0.5, (double)(st)*(S)*(R)*0.5
#define LVL(st) WH(st,RQ0,SC0), WH(st,RQ0,SC1), WH(st,RQ0,SC2), \
                WH(st,RQ1,SC0), WH(st,RQ1,SC1), WH(st,RQ1,SC2), \
                WH(st,RQ2,SC0), WH(st,RQ2,SC1), WH(st,RQ2,SC2)
__constant__ double WH2[5][9][2] = { {LVL(8)}, {LVL(16)}, {LVL(32)}, {LVL(64)}, {LVL(128)} };

__device__ __forceinline__ float frcp(float x){ return __builtin_amdgcn_rcpf(x); }
__device__ __forceinline__ float fexp2(float x){ return __builtin_amdgcn_exp2f(x); }
__device__ __forceinline__ float flog2(float x){ return __builtin_amdgcn_logf(x); }

// p(x)^2 * softplus(x)/LN2  (caller scales by 0.75*LN2)
__device__ __forceinline__ float f0_term(float x){
  float xl = x * LOG2E;
  float mx = fmaxf(xl, 0.f);
  float mn = fminf(xl, 0.f);
  float u  = fexp2(mn - mx);      // e^{-|x|}
  float w  = 1.0f + u;
  float lw = flog2(w);
  float g  = mn - lw;             // log2(sigmoid)
  return fexp2(g + g) * (lw + mx);
}

// (f1 - f0) correction for the one-hot label class (absolute units)
__device__ __forceinline__ float corr_term(float x){
  float xl = x * LOG2E;
  float mx = fmaxf(xl, 0.f);
  float mn = fminf(xl, 0.f);
  float u  = fexp2(mn - mx);
  float w  = 1.0f + u;
  float lw = flog2(w);
  float p2   = fexp2(2.f * (mn - lw));
  float omp2 = fexp2(-2.f * (mx + lw));
  float sp   = LN2 * (lw + mx);
  float spn  = LN2 * (lw - mn);
  return 0.25f * omp2 * spn - 0.75f * p2 * sp;
}

// anchor geometry from table (f64 subtract matches numpy bit-exactly)
__device__ __forceinline__ void anchor_geom(int a, float& x1, float& y1,
                                            float& x2, float& y2){
  int lv, lg, st, rel;
  if      (a < 36864){ lv = 0; lg = 6; st = 8;   rel = a; }
  else if (a < 46080){ lv = 1; lg = 5; st = 16;  rel = a - 36864; }
  else if (a < 48384){ lv = 2; lg = 4; st = 32;  rel = a - 46080; }
  else if (a < 48960){ lv = 3; lg = 3; st = 64;  rel = a - 48384; }
  else               { lv = 4; lg = 2; st = 128; rel = a - 48960; }
  int cell = rel / 9;
  int k    = rel - cell * 9;
  int yy   = cell >> lg;
  int xx   = cell & ((1 << lg) - 1);
  double w2 = WH2[lv][k][0], h2 = WH2[lv][k][1];
  double cxd = ((double)xx + 0.5) * (double)st;
  double cyd = ((double)yy + 0.5) * (double)st;
  x1 = (float)(cxd - w2);
  y1 = (float)(cyd - h2);
  x2 = (float)(cxd + w2);
  y2 = (float)(cyd + h2);
}

__global__ __launch_bounds__(256, 6) void fused_loss_kernel(
    const float* __restrict__ cls,
    const float* __restrict__ bbox,
    const float* __restrict__ gtb,
    const int*   __restrict__ gtl,
    const unsigned char* __restrict__ gmask,
    float* __restrict__ ws)
{
  const int tid = threadIdx.x;
  const int wv = tid >> 6, ln = tid & 63;
  const int b  = blockIdx.y;
  const int blkx = blockIdx.x;
  const int a0 = blkx * APB;
  const int bid = b * BPI + blkx;
  const int nvalid = min(N_ANCH - a0, APB);
  const int nf4 = nvalid * ROW_F4;

  __shared__ float4 s_cgt[NGT + 4];
  __shared__ float  s_carea[NGT + 4];
  __shared__ int    s_clab[NGT + 4];
  __shared__ float  s_wmin[4], s_wmax[4];
  __shared__ float  s_r0[4], s_r1[4], s_r2[4];
  __shared__ int    s_cnt;

  const float* clsbase = cls + (size_t)(b * N_ANCH + a0) * NC;
  const float4* cp = (const float4*)clsbase;

  float s0 = 0.f, s1 = 0.f, s2 = 0.f, s3 = 0.f;
  float accB = 0.f, posf = 0.f;
  int   labr[2]; float wr[2];          // per-thread row results (regs, no LDS)

  const bool streamFirst = ((blkx + b) & 1) != 0;

  // ================= UNWEIGHTED f0 STREAM (half the blocks run it first) ====
  #define STREAM_LOOP                                           \
    _Pragma("unroll 2")                                         \
    for (int i = tid; i < nf4; i += 256){                       \
      float4 c4 = cp[i];                                        \
      s0 += f0_term(c4.x);                                      \
      s1 += f0_term(c4.y);                                      \
      s2 += f0_term(c4.z);                                      \
      s3 += f0_term(c4.w);                                      \
    }

  if (streamFirst){ STREAM_LOOP }

  // ================= ASSIGNMENT (all 4 waves, 2 anchors/thread) =============
  float ax1[2], ay1[2], ax2[2], ay2[2];
  #pragma unroll
  for (int r = 0; r < 2; ++r){
    int a = a0 + r * 256 + tid;
    if (a < N_ANCH){
      anchor_geom(a, ax1[r], ay1[r], ax2[r], ay2[r]);
    } else {
      ax1[r] = 0.f; ay1[r] = 3.0e38f; ax2[r] = 0.f; ay2[r] = -3.0e38f;
    }
  }
  {
    float wy1 = fminf(ay1[0], ay1[1]);
    float wy2 = fmaxf(ay2[0], ay2[1]);
    #pragma unroll
    for (int o = 32; o > 0; o >>= 1){
      wy1 = fminf(wy1, __shfl_down(wy1, o));
      wy2 = fmaxf(wy2, __shfl_down(wy2, o));
    }
    if (ln == 0){ s_wmin[wv] = wy1; s_wmax[wv] = wy2; }
  }
  __syncthreads();

  if (wv == 0){
    // mask layout detection (bool8 vs int32 vs float32), wave-local
    const unsigned int* mw = (const unsigned int*)gmask;
    bool nf = false, ob = false;
    for (int i = ln; i < (NB_IMG * NGT) / 4; i += 64){
      unsigned int w = mw[i];
      nf |= (w != 0u && w != 0x3F800000u);
      ob |= ((w & 0xFFFFFF00u) != 0u);
    }
    bool byteLayout = __any((int)nf) && __any((int)ob);
    float ymin = fminf(fminf(s_wmin[0], s_wmin[1]), fminf(s_wmin[2], s_wmin[3]));
    float ymax = fmaxf(fmaxf(s_wmax[0], s_wmax[1]), fmaxf(s_wmax[2], s_wmax[3]));
    const float4* g4 = (const float4*)gtb;

    // GT staging, y-prefilter (exact: fail => IoU == 0), ordered compaction
    float4 g = g4[b * NGT + ln];
    int v = byteLayout ? (gmask[b * NGT + ln] != 0)
                       : (((const unsigned int*)gmask)[b * NGT + ln] != 0u);
    bool pass = v && (g.y < ymax) && (g.w > ymin);
    unsigned long long bal = __ballot(pass);
    int pre = __popcll(bal & ((1ull << ln) - 1ull));
    if (pass){
      s_cgt[pre] = g;
      s_carea[pre] = (g.z - g.x) * (g.w - g.y);
      s_clab[pre] = gtl[b * NGT + ln];
    }
    int c0 = __popcll(bal);
    bool pass1 = false; float4 g1;
    if (ln < NGT - 64){
      g1 = g4[b * NGT + 64 + ln];
      int v1 = byteLayout ? (gmask[b * NGT + 64 + ln] != 0)
                          : (((const unsigned int*)gmask)[b * NGT + 64 + ln] != 0u);
      pass1 = v1 && (g1.y < ymax) && (g1.w > ymin);
    }
    unsigned long long bal1 = __ballot(pass1);
    int pre1 = c0 + __popcll(bal1 & ((1ull << ln) - 1ull));
    if (pass1){
      s_cgt[pre1] = g1;
      s_carea[pre1] = (g1.z - g1.x) * (g1.w - g1.y);
      s_clab[pre1] = gtl[b * NGT + 64 + ln];
    }
    if (ln == 0){
      int cnt = c0 + __popcll(bal1);
      float4 far4; far4.x = 3e9f; far4.y = 3e9f; far4.z = 3e9f; far4.w = 3e9f;
      s_cgt[cnt] = far4;     s_carea[cnt] = 0.f;     s_clab[cnt] = 0;
      s_cgt[cnt + 1] = far4; s_carea[cnt + 1] = 0.f; s_clab[cnt + 1] = 0;
      s_cnt = (cnt + 1) & ~1;   // even, >= 2
    }
  }
  __syncthreads();

  {
    const int cntp = s_cnt;
    #pragma unroll
    for (int r = 0; r < 2; ++r){
      int a = a0 + r * 256 + tid;
      float x1 = ax1[r], y1 = ay1[r], x2 = ax2[r], y2 = ay2[r];
      float areaA = (x2 - x1) * (y2 - y1);
      // division-free argmax: track (Ib,Ub), compare I*Ub > Ib*U
      float Ib = -1.f, Ub = 1.f; int best = 0;
      for (int j = 0; j < cntp; j += 2){
        #pragma unroll
        for (int u2 = 0; u2 < 2; ++u2){
          int jj = j + u2;
          float4 gg = s_cgt[jj];
          float lx = fmaxf(x1, gg.x), ly = fmaxf(y1, gg.y);
          float rx = fminf(x2, gg.z), ry = fminf(y2, gg.w);
          float iw = fmaxf(rx - lx, 0.f), ih = fmaxf(ry - ly, 0.f);
          float I  = iw * ih;
          float U  = (areaA + s_carea[jj]) - I;
          bool gt = I * Ub > Ib * U;
          best = gt ? jj : best;
          Ib = gt ? I : Ib;
          Ub = gt ? U : Ub;
        }
      }
      bool va  = a < N_ANCH;
      bool pos = va && (2.f * Ib >= Ub);                     // iou >= 0.5
      bool ign = va && !pos && (5.f * Ib >= 2.f * Ub);       // 0.4 <= iou < 0.5
      wr[r]   = ign ? 0.f : 1.f;
      labr[r] = pos ? s_clab[best] : -1;

      if (pos){
        posf += 1.f;
        float4 gg = s_cgt[best];
        float aw = x2 - x1, ah = y2 - y1;
        float axc = (x1 + x2) * 0.5f, ayc = (y1 + y2) * 0.5f;
        float gw = fmaxf(gg.z - gg.x, 1e-6f), gh = fmaxf(gg.w - gg.y, 1e-6f);
        float gxc = (gg.x + gg.z) * 0.5f, gyc = (gg.y + gg.w) * 0.5f;
        float t0 = (gxc - axc) / aw, t1 = (gyc - ayc) / ah;
        float t2 = LN2 * flog2(gw * frcp(aw));
        float t3 = LN2 * flog2(gh * frcp(ah));
        float4 bp = ((const float4*)bbox)[(size_t)b * N_ANCH + a0 + r * 256 + tid];
        const float BETA = 1.0f / 9.0f;
        float d0 = fabsf(bp.x - t0), d1 = fabsf(bp.y - t1);
        float d2 = fabsf(bp.z - t2), d3 = fabsf(bp.w - t3);
        accB += (d0 < BETA) ? 4.5f * d0 * d0 : d0 - 0.5f * BETA;
        accB += (d1 < BETA) ? 4.5f * d1 * d1 : d1 - 0.5f * BETA;
        accB += (d2 < BETA) ? 4.5f * d2 * d2 : d2 - 0.5f * BETA;
        accB += (d3 < BETA) ? 4.5f * d3 * d3 : d3 - 0.5f * BETA;
      }
    }
  }

  if (!streamFirst){ STREAM_LOOP }

  // ================= CORRECTIONS (same thread that assigned the row) ========
  float fsub = 0.f, fcorr = 0.f;
  #pragma unroll
  for (int r = 0; r < 2; ++r){
    int row = r * 256 + tid;
    if (row < nvalid){
      int lab = labr[r];
      if (lab >= 0) fcorr += corr_term(clsbase[row * NC + lab]);
      if (wr[r] == 0.f){
        const float4* rp = cp + row * ROW_F4;
        float t0 = 0.f, t1 = 0.f, t2 = 0.f, t3 = 0.f;
        #pragma unroll 5
        for (int k2 = 0; k2 < ROW_F4; ++k2){
          float4 c4 = rp[k2];
          t0 += f0_term(c4.x); t1 += f0_term(c4.y);
          t2 += f0_term(c4.z); t3 += f0_term(c4.w);
        }
        fsub += (t0 + t1) + (t2 + t3);
      }
    }
  }
  float accC = fmaf(FSCALE, ((s0 + s1) + (s2 + s3)) - fsub, fcorr);

  // ================= block reduction =================
  #pragma unroll
  for (int o = 32; o > 0; o >>= 1){
    accC += __shfl_down(accC, o);
    accB += __shfl_down(accB, o);
    posf += __shfl_down(posf, o);
  }
  if (ln == 0){ s_r0[wv] = accC; s_r1[wv] = accB; s_r2[wv] = posf; }
  __syncthreads();
  if (tid == 0){
    ws[bid]         = s_r0[0] + s_r0[1] + s_r0[2] + s_r0[3];
    ws[OFF_B + bid] = s_r1[0] + s_r1[1] + s_r1[2] + s_r1[3];
    ws[OFF_P + bid] = s_r2[0] + s_r2[1] + s_r2[2] + s_r2[3];
  }
}

__global__ void finalize_kernel(const float* __restrict__ ws,
                                float* __restrict__ out)
{
  __shared__ float sC[NB_IMG], sB[NB_IMG];
  const int tid = threadIdx.x;          // 512 threads = 8 waves
  const int wv = tid >> 6, ln = tid & 63;
  #pragma unroll
  for (int i = 0; i < 2; ++i){
    int b = wv * 2 + i;
    float c = 0.f, bb = 0.f, p = 0.f;
    for (int k = ln; k < BPI; k += 64){
      c  += ws[b * BPI + k];
      bb += ws[OFF_B + b * BPI + k];
      p  += ws[OFF_P + b * BPI + k];
    }
    #pragma unroll
    for (int o = 32; o > 0; o >>= 1){
      c += __shfl_down(c, o); bb += __shfl_down(bb, o); p += __shfl_down(p, o);
    }
    if (ln == 0){
      float tot = fmaxf(p, 1.f);
      sC[b] = c / tot;
      sB[b] = bb / tot;
    }
  }
  __syncthreads();
  if (tid == 0){
    float lc = 0.f, lb = 0.f;
    #pragma unroll
    for (int b = 0; b < NB_IMG; ++b){ lc += sC[b]; lb += sB[b]; }
    out[0] = lc / 16.f;
    out[1] = 10.f * lb / 16.f;
  }
}

extern "C" void kernel_launch(void* const* d_in, const int* in_sizes, int n_in,
                              void* d_out, int out_size, void* d_ws, size_t ws_size,
                              hipStream_t stream) {
  const float* cls  = (const float*)d_in[0];
  const float* bbox = (const float*)d_in[1];
  const float* gtb  = (const float*)d_in[2];
  const int*   gtl  = (const int*)d_in[3];
  const unsigned char* gmask = (const unsigned char*)d_in[4];

  float* ws = (float*)d_ws;   // 3*NBLK floats, fully overwritten every call

  dim3 grid(BPI, NB_IMG);
  fused_loss_kernel<<<grid, 256, 0, stream>>>(cls, bbox, gtb, gtl, gmask, ws);
  finalize_kernel<<<1, 512, 0, stream>>>(ws, (float*)d_out);
}

// Round 8
// 66.138 us; speedup vs baseline: 1.3532x; 1.0954x over previous
//
#include <hip/hip_runtime.h>

#define N_ANCH 49104
#define NB_IMG 16
#define NGT 100
#define NC 80
#define BPI 96                 // blocks per image
#define APB 512                // anchors (rows) per block
#define NBLK (BPI * NB_IMG)    // 1536
#define ROW_F4 (NC / 4)        // 20 float4 per row
#define LABSTRIDE (BPI * APB)  // 49152 bytes per image (padded)

#define LOG2E 1.4426950408889634f
#define LN2   0.6931471805599453f
#define FSCALE (0.75f * LN2)

#define LAB_NEG 200
#define LAB_IGN 201

__device__ __forceinline__ float frcp(float x){ return __builtin_amdgcn_rcpf(x); }
__device__ __forceinline__ float fexp2(float x){ return __builtin_amdgcn_exp2f(x); }
__device__ __forceinline__ float flog2(float x){ return __builtin_amdgcn_logf(x); }

// p(x)^2 * softplus(x)/LN2  (caller scales by 0.75*LN2)
__device__ __forceinline__ float f0_term(float x){
  float xl = x * LOG2E;
  float mx = fmaxf(xl, 0.f);
  float mn = fminf(xl, 0.f);
  float u  = fexp2(mn - mx);      // e^{-|x|}
  float w  = 1.0f + u;
  float lw = flog2(w);
  float g  = mn - lw;             // log2(sigmoid)
  return fexp2(g + g) * (lw + mx);
}

// (f1 - f0) correction for the one-hot label class (absolute units)
__device__ __forceinline__ float corr_term(float x){
  float xl = x * LOG2E;
  float mx = fmaxf(xl, 0.f);
  float mn = fminf(xl, 0.f);
  float u  = fexp2(mn - mx);
  float w  = 1.0f + u;
  float lw = flog2(w);
  float p2   = fexp2(2.f * (mn - lw));
  float omp2 = fexp2(-2.f * (mx + lw));
  float sp   = LN2 * (lw + mx);
  float spn  = LN2 * (lw - mn);
  return 0.25f * omp2 * spn - 0.75f * p2 * sp;
}

// anchor geometry, inline f64 (R5-proven bit-match to numpy)
__device__ __forceinline__ void anchor_geom(int a, float& x1, float& y1,
                                            float& x2, float& y2){
  int lg, st, rel;
  if      (a < 36864){ lg = 6; st = 8;   rel = a; }
  else if (a < 46080){ lg = 5; st = 16;  rel = a - 36864; }
  else if (a < 48384){ lg = 4; st = 32;  rel = a - 46080; }
  else if (a < 48960){ lg = 3; st = 64;  rel = a - 48384; }
  else               { lg = 2; st = 128; rel = a - 48960; }
  int cell = rel / 9;
  int k    = rel - cell * 9;
  int yy   = cell >> lg;
  int xx   = cell & ((1 << lg) - 1);
  int rr = (k >= 6) ? 2 : ((k >= 3) ? 1 : 0);
  int sc = k - rr * 3;
  double sq  = (rr == 0) ? 0.7071067811865476 : ((rr == 1) ? 1.0 : 1.4142135623730951);
  double scl = (sc == 0) ? 4.0 : ((sc == 1) ? 5.039684199579493 : 6.349604207872798);
  double ss  = (double)st * scl;
  double wd  = ss / sq, hd = ss * sq;
  double cxd = ((double)xx + 0.5) * (double)st;
  double cyd = ((double)yy + 0.5) * (double)st;
  x1 = (float)(cxd - wd * 0.5);
  y1 = (float)(cyd - hd * 0.5);
  x2 = (float)(cxd + wd * 0.5);
  y2 = (float)(cyd + hd * 0.5);
}

// =================== K1: assignment ===================
__global__ __launch_bounds__(256, 6) void assign_kernel(
    const float* __restrict__ bbox,
    const float* __restrict__ gtb,
    const int*   __restrict__ gtl,
    const unsigned char* __restrict__ gmask,
    unsigned char* __restrict__ lab,   // [NB_IMG * LABSTRIDE]
    float* __restrict__ bbP,           // [NBLK] smooth-l1 partial
    float* __restrict__ posP)          // [NBLK] pos count partial
{
  const int tid = threadIdx.x;
  const int wv = tid >> 6, ln = tid & 63;
  const int b  = blockIdx.y;
  const int blkx = blockIdx.x;
  const int a0 = blkx * APB;
  const int bid = b * BPI + blkx;

  __shared__ float4 s_cgt[NGT + 4];
  __shared__ float  s_carea[NGT + 4];
  __shared__ int    s_clab[NGT + 4];
  __shared__ float  s_wmin[4], s_wmax[4];
  __shared__ float  s_r1[4], s_r2[4];
  __shared__ int    s_cnt;

  // ---- per-thread geometry for 2 anchors ----
  float ax1[2], ay1[2], ax2[2], ay2[2];
  #pragma unroll
  for (int r = 0; r < 2; ++r){
    int a = a0 + r * 256 + tid;
    if (a < N_ANCH){
      anchor_geom(a, ax1[r], ay1[r], ax2[r], ay2[r]);
    } else {
      ax1[r] = 0.f; ay1[r] = 3.0e38f; ax2[r] = 0.f; ay2[r] = -3.0e38f;
    }
  }
  // ---- block y-extent ----
  {
    float wy1 = fminf(ay1[0], ay1[1]);
    float wy2 = fmaxf(ay2[0], ay2[1]);
    #pragma unroll
    for (int o = 32; o > 0; o >>= 1){
      wy1 = fminf(wy1, __shfl_down(wy1, o));
      wy2 = fmaxf(wy2, __shfl_down(wy2, o));
    }
    if (ln == 0){ s_wmin[wv] = wy1; s_wmax[wv] = wy2; }
  }
  __syncthreads();

  if (wv == 0){
    // mask layout detection (bool8 vs int32 vs float32)
    const unsigned int* mw = (const unsigned int*)gmask;
    bool nf = false, ob = false;
    for (int i = ln; i < (NB_IMG * NGT) / 4; i += 64){
      unsigned int w = mw[i];
      nf |= (w != 0u && w != 0x3F800000u);
      ob |= ((w & 0xFFFFFF00u) != 0u);
    }
    bool byteLayout = __any((int)nf) && __any((int)ob);
    float ymin = fminf(fminf(s_wmin[0], s_wmin[1]), fminf(s_wmin[2], s_wmin[3]));
    float ymax = fmaxf(fmaxf(s_wmax[0], s_wmax[1]), fmaxf(s_wmax[2], s_wmax[3]));
    const float4* g4 = (const float4*)gtb;

    // GT staging, y-prefilter (exact: fail => IoU == 0), ordered compaction
    float4 g = g4[b * NGT + ln];
    int v = byteLayout ? (gmask[b * NGT + ln] != 0)
                       : (((const unsigned int*)gmask)[b * NGT + ln] != 0u);
    bool pass = v && (g.y < ymax) && (g.w > ymin);
    unsigned long long bal = __ballot(pass);
    int pre = __popcll(bal & ((1ull << ln) - 1ull));
    if (pass){
      s_cgt[pre] = g;
      s_carea[pre] = (g.z - g.x) * (g.w - g.y);
      s_clab[pre] = gtl[b * NGT + ln];
    }
    int c0 = __popcll(bal);
    bool pass1 = false; float4 g1;
    if (ln < NGT - 64){
      g1 = g4[b * NGT + 64 + ln];
      int v1 = byteLayout ? (gmask[b * NGT + 64 + ln] != 0)
                          : (((const unsigned int*)gmask)[b * NGT + 64 + ln] != 0u);
      pass1 = v1 && (g1.y < ymax) && (g1.w > ymin);
    }
    unsigned long long bal1 = __ballot(pass1);
    int pre1 = c0 + __popcll(bal1 & ((1ull << ln) - 1ull));
    if (pass1){
      s_cgt[pre1] = g1;
      s_carea[pre1] = (g1.z - g1.x) * (g1.w - g1.y);
      s_clab[pre1] = gtl[b * NGT + 64 + ln];
    }
    if (ln == 0){
      int cnt = c0 + __popcll(bal1);
      float4 far4; far4.x = 3e9f; far4.y = 3e9f; far4.z = 3e9f; far4.w = 3e9f;
      s_cgt[cnt] = far4;     s_carea[cnt] = 0.f;     s_clab[cnt] = 0;
      s_cgt[cnt + 1] = far4; s_carea[cnt + 1] = 0.f; s_clab[cnt + 1] = 0;
      s_cnt = (cnt + 1) & ~1;   // even, >= 2
    }
  }
  __syncthreads();

  float accB = 0.f, posf = 0.f;
  const int cntp = s_cnt;
  #pragma unroll
  for (int r = 0; r < 2; ++r){
    int a = a0 + r * 256 + tid;
    float x1 = ax1[r], y1 = ay1[r], x2 = ax2[r], y2 = ay2[r];
    float areaA = (x2 - x1) * (y2 - y1);
    // division-free argmax (R2-verified): track (Ib,Ub), compare I*Ub > Ib*U
    float Ib = -1.f, Ub = 1.f; int best = 0;
    for (int j = 0; j < cntp; j += 2){
      #pragma unroll
      for (int u2 = 0; u2 < 2; ++u2){
        int jj = j + u2;
        float4 gg = s_cgt[jj];
        float lx = fmaxf(x1, gg.x), ly = fmaxf(y1, gg.y);
        float rx = fminf(x2, gg.z), ry = fminf(y2, gg.w);
        float iw = fmaxf(rx - lx, 0.f), ih = fmaxf(ry - ly, 0.f);
        float I  = iw * ih;
        float U  = (areaA + s_carea[jj]) - I;
        bool gt = I * Ub > Ib * U;
        best = gt ? jj : best;
        Ib = gt ? I : Ib;
        Ub = gt ? U : Ub;
      }
    }
    bool va  = a < N_ANCH;
    bool pos = va && (2.f * Ib >= Ub);                   // iou >= 0.5
    bool ign = !pos && (5.f * Ib >= 2.f * Ub);           // 0.4 <= iou < 0.5
    unsigned char lb = pos ? (unsigned char)s_clab[best]
                           : ((ign || !va) ? (unsigned char)LAB_IGN
                                           : (unsigned char)LAB_NEG);
    lab[(size_t)b * LABSTRIDE + a0 + r * 256 + tid] = lb;

    if (pos){
      posf += 1.f;
      float4 gg = s_cgt[best];
      float aw = x2 - x1, ah = y2 - y1;
      float axc = (x1 + x2) * 0.5f, ayc = (y1 + y2) * 0.5f;
      float gw = fmaxf(gg.z - gg.x, 1e-6f), gh = fmaxf(gg.w - gg.y, 1e-6f);
      float gxc = (gg.x + gg.z) * 0.5f, gyc = (gg.y + gg.w) * 0.5f;
      float t0 = (gxc - axc) / aw, t1 = (gyc - ayc) / ah;
      float t2 = LN2 * flog2(gw * frcp(aw));
      float t3 = LN2 * flog2(gh * frcp(ah));
      float4 bp = ((const float4*)bbox)[(size_t)b * N_ANCH + a];
      const float BETA = 1.0f / 9.0f;
      float d0 = fabsf(bp.x - t0), d1 = fabsf(bp.y - t1);
      float d2 = fabsf(bp.z - t2), d3 = fabsf(bp.w - t3);
      accB += (d0 < BETA) ? 4.5f * d0 * d0 : d0 - 0.5f * BETA;
      accB += (d1 < BETA) ? 4.5f * d1 * d1 : d1 - 0.5f * BETA;
      accB += (d2 < BETA) ? 4.5f * d2 * d2 : d2 - 0.5f * BETA;
      accB += (d3 < BETA) ? 4.5f * d3 * d3 : d3 - 0.5f * BETA;
    }
  }

  #pragma unroll
  for (int o = 32; o > 0; o >>= 1){
    accB += __shfl_down(accB, o);
    posf += __shfl_down(posf, o);
  }
  if (ln == 0){ s_r1[wv] = accB; s_r2[wv] = posf; }
  __syncthreads();
  if (tid == 0){
    bbP[bid]  = s_r1[0] + s_r1[1] + s_r1[2] + s_r1[3];
    posP[bid] = s_r2[0] + s_r2[1] + s_r2[2] + s_r2[3];
  }
}

// =================== K2: weighted f0 stream (R5 body) ===================
__global__ __launch_bounds__(256, 6) void stream_kernel(
    const float* __restrict__ cls,
    const unsigned char* __restrict__ lab,
    float* __restrict__ clsP)          // [NBLK]
{
  const int tid = threadIdx.x;
  const int wv = tid >> 6, ln = tid & 63;
  const int b  = blockIdx.y;
  const int a0 = blockIdx.x * APB;
  const int bid = b * BPI + blockIdx.x;
  const int nvalid = min(N_ANCH - a0, APB);
  const int nf4 = nvalid * ROW_F4;

  __shared__ unsigned char s_lab[APB];
  __shared__ float s_r0[4];

  // stage labels (coalesced bytes; pad rows are LAB_IGN, never streamed)
  #pragma unroll
  for (int j = 0; j < 2; ++j)
    s_lab[j * 256 + tid] = lab[(size_t)b * LABSTRIDE + a0 + j * 256 + tid];
  __syncthreads();

  const float4* cp = (const float4*)(cls + (size_t)(b * N_ANCH + a0) * NC);
  float fraw = 0.f, fcorr = 0.f;
  for (int i = tid; i < nf4; i += 256){
    float4 c4 = cp[i];
    int row = i / 20;                 // const-div -> mul/shift
    int cb  = (i - row * 20) * 4;     // first class of this float4
    float s = (f0_term(c4.x) + f0_term(c4.y)) + (f0_term(c4.z) + f0_term(c4.w));
    int li = (int)s_lab[row];
    float wf = (li == LAB_IGN) ? 0.f : 1.f;
    fraw = fmaf(wf, s, fraw);
    if ((unsigned)(li - cb) < 4u){    // label in this float4 (200/201 never hit)
      int o = li - cb;
      float xe = (o == 0) ? c4.x : (o == 1) ? c4.y : (o == 2) ? c4.z : c4.w;
      fcorr += corr_term(xe);
    }
  }
  float accC = fmaf(FSCALE, fraw, fcorr);

  #pragma unroll
  for (int o = 32; o > 0; o >>= 1) accC += __shfl_down(accC, o);
  if (ln == 0) s_r0[wv] = accC;
  __syncthreads();
  if (tid == 0) clsP[bid] = s_r0[0] + s_r0[1] + s_r0[2] + s_r0[3];
}

// =================== finalize ===================
__global__ void finalize_kernel(const float* __restrict__ clsP,
                                const float* __restrict__ bbP,
                                const float* __restrict__ posP,
                                float* __restrict__ out)
{
  __shared__ float sC[NB_IMG], sB[NB_IMG];
  const int tid = threadIdx.x;          // 512 threads = 8 waves
  const int wv = tid >> 6, ln = tid & 63;
  #pragma unroll
  for (int i = 0; i < 2; ++i){
    int b = wv * 2 + i;
    float c = 0.f, bb = 0.f, p = 0.f;
    for (int k = ln; k < BPI; k += 64){
      c  += clsP[b * BPI + k];
      bb += bbP[b * BPI + k];
      p  += posP[b * BPI + k];
    }
    #pragma unroll
    for (int o = 32; o > 0; o >>= 1){
      c += __shfl_down(c, o); bb += __shfl_down(bb, o); p += __shfl_down(p, o);
    }
    if (ln == 0){
      float tot = fmaxf(p, 1.f);
      sC[b] = c / tot;
      sB[b] = bb / tot;
    }
  }
  __syncthreads();
  if (tid == 0){
    float lc = 0.f, lb = 0.f;
    #pragma unroll
    for (int b = 0; b < NB_IMG; ++b){ lc += sC[b]; lb += sB[b]; }
    out[0] = lc / 16.f;
    out[1] = 10.f * lb / 16.f;
  }
}

extern "C" void kernel_launch(void* const* d_in, const int* in_sizes, int n_in,
                              void* d_out, int out_size, void* d_ws, size_t ws_size,
                              hipStream_t stream) {
  const float* cls  = (const float*)d_in[0];
  const float* bbox = (const float*)d_in[1];
  const float* gtb  = (const float*)d_in[2];
  const int*   gtl  = (const int*)d_in[3];
  const unsigned char* gmask = (const unsigned char*)d_in[4];

  // ws layout: lab bytes [0, 786432) ; then 3 float arrays of NBLK
  unsigned char* labbuf = (unsigned char*)d_ws;
  float* wsf  = (float*)((char*)d_ws + (size_t)NB_IMG * LABSTRIDE);
  float* bbP  = wsf;
  float* posP = wsf + NBLK;
  float* clsP = wsf + 2 * NBLK;

  dim3 grid(BPI, NB_IMG);
  assign_kernel<<<grid, 256, 0, stream>>>(bbox, gtb, gtl, gmask, labbuf, bbP, posP);
  stream_kernel<<<grid, 256, 0, stream>>>(cls, labbuf, clsP);
  finalize_kernel<<<1, 512, 0, stream>>>(clsP, bbP, posP, (float*)d_out);
}

// Round 9
// 56.166 us; speedup vs baseline: 1.5934x; 1.1776x over previous
//
#include <hip/hip_runtime.h>

#define N_ANCH 49104
#define NB_IMG 16
#define NGT 100
#define NC 80
#define BPI 96                 // blocks per image
#define APB 512                // anchors (rows) per block
#define NBLK (BPI * NB_IMG)    // 1536
#define ROW_F4 (NC / 4)        // 20 float4 per row
#define MAXG 104               // per-wave filtered GT capacity (100 + sentinels)

#define LOG2E 1.4426950408889634f
#define LN2   0.6931471805599453f
#define FSCALE (0.75f * LN2)

// compile-time f32 half-extents per (ratio,scale) pair k = rr*3 + sc,
// rounded from exact f64 (w2 = scale/sqrt(ratio)*0.5; st is a power of two
// so st*BW9[k] is an exact f32 scaling).
__constant__ float BW9[9] = {
  (float)(4.0               / 0.7071067811865476 * 0.5),
  (float)(5.039684199579493 / 0.7071067811865476 * 0.5),
  (float)(6.349604207872798 / 0.7071067811865476 * 0.5),
  (float)(4.0               * 0.5),
  (float)(5.039684199579493 * 0.5),
  (float)(6.349604207872798 * 0.5),
  (float)(4.0               / 1.4142135623730951 * 0.5),
  (float)(5.039684199579493 / 1.4142135623730951 * 0.5),
  (float)(6.349604207872798 / 1.4142135623730951 * 0.5),
};
__constant__ float BH9[9] = {
  (float)(4.0               * 0.7071067811865476 * 0.5),
  (float)(5.039684199579493 * 0.7071067811865476 * 0.5),
  (float)(6.349604207872798 * 0.7071067811865476 * 0.5),
  (float)(4.0               * 0.5),
  (float)(5.039684199579493 * 0.5),
  (float)(6.349604207872798 * 0.5),
  (float)(4.0               * 1.4142135623730951 * 0.5),
  (float)(5.039684199579493 * 1.4142135623730951 * 0.5),
  (float)(6.349604207872798 * 1.4142135623730951 * 0.5),
};

__device__ __forceinline__ float frcp(float x){ return __builtin_amdgcn_rcpf(x); }
__device__ __forceinline__ float fexp2(float x){ return __builtin_amdgcn_exp2f(x); }
__device__ __forceinline__ float flog2(float x){ return __builtin_amdgcn_logf(x); }

// p(x)^2 * softplus(x)/LN2  (caller scales by 0.75*LN2)
__device__ __forceinline__ float f0_term(float x){
  float xl = x * LOG2E;
  float mx = fmaxf(xl, 0.f);
  float mn = fminf(xl, 0.f);
  float u  = fexp2(mn - mx);      // e^{-|x|}
  float w  = 1.0f + u;
  float lw = flog2(w);
  float g  = mn - lw;             // log2(sigmoid)
  return fexp2(g + g) * (lw + mx);
}
__device__ __forceinline__ float f0x4(float4 c4){
  return (f0_term(c4.x) + f0_term(c4.y)) + (f0_term(c4.z) + f0_term(c4.w));
}

// (f1 - f0) correction for the one-hot label class (absolute units)
__device__ __forceinline__ float corr_term(float x){
  float xl = x * LOG2E;
  float mx = fmaxf(xl, 0.f);
  float mn = fminf(xl, 0.f);
  float u  = fexp2(mn - mx);
  float w  = 1.0f + u;
  float lw = flog2(w);
  float p2   = fexp2(2.f * (mn - lw));
  float omp2 = fexp2(-2.f * (mx + lw));
  float sp   = LN2 * (lw + mx);
  float spn  = LN2 * (lw - mn);
  return 0.25f * omp2 * spn - 0.75f * p2 * sp;
}

// f32 anchor geometry (table-based, no f64, no divides)
__device__ __forceinline__ void anchor_geom(int a, float& x1, float& y1,
                                            float& x2, float& y2){
  int lg, st, rel;
  if      (a < 36864){ lg = 6; st = 8;   rel = a; }
  else if (a < 46080){ lg = 5; st = 16;  rel = a - 36864; }
  else if (a < 48384){ lg = 4; st = 32;  rel = a - 46080; }
  else if (a < 48960){ lg = 3; st = 64;  rel = a - 48384; }
  else               { lg = 2; st = 128; rel = a - 48960; }
  int cell = rel / 9;
  int k    = rel - cell * 9;
  int yy   = cell >> lg;
  int xx   = cell & ((1 << lg) - 1);
  float stf = (float)st;
  float cx = ((float)xx + 0.5f) * stf;   // exact in f32
  float cy = ((float)yy + 0.5f) * stf;
  float w2 = stf * BW9[k];               // exact scaling of correctly-rounded base
  float h2 = stf * BH9[k];
  x1 = cx - w2; y1 = cy - h2; x2 = cx + w2; y2 = cy + h2;
}

__global__ __launch_bounds__(256, 6) void fused_loss_kernel(
    const float* __restrict__ cls,
    const float* __restrict__ bbox,
    const float* __restrict__ gtb,
    const int*   __restrict__ gtl,
    const unsigned char* __restrict__ gmask,
    float* __restrict__ ws)
{
  const int tid = threadIdx.x;
  const int wv = tid >> 6, ln = tid & 63;
  const int b  = blockIdx.y;
  const int a0 = blockIdx.x * APB;
  const int bid = b * BPI + blockIdx.x;
  const int nvalid = min(N_ANCH - a0, APB);
  const int nf4 = nvalid * ROW_F4;       // >= 9280 always

  __shared__ float4 s_cgt[4][MAXG];
  __shared__ float  s_carea[4][MAXG];
  __shared__ int    s_clab[4][MAXG];
  __shared__ float  s_wf[APB];           // 1 = counted (pos|neg), 0 = ignored
  __shared__ float  s_r0[4], s_r1[4], s_r2[4];

  const float* clsbase = cls + (size_t)(b * N_ANCH + a0) * NC;
  const float4* cp = (const float4*)clsbase;

  // ---- prefetch first 2 stream iterations (issue at cycle ~0) ----
  float4 pf0 = cp[tid];
  float4 pf1 = cp[tid + 256];

  // ---- f32 geometry for this thread's 2 anchors ----
  float ax1[2], ay1[2], ax2[2], ay2[2];
  #pragma unroll
  for (int r = 0; r < 2; ++r){
    int a = a0 + r * 256 + tid;
    if (a < N_ANCH) anchor_geom(a, ax1[r], ay1[r], ax2[r], ay2[r]);
    else { ax1[r] = 0.f; ay1[r] = 3.0e38f; ax2[r] = 0.f; ay2[r] = -3.0e38f; }
  }

  // ---- per-wave y-extent (no LDS, no barrier) ----
  float ymin = fminf(ay1[0], ay1[1]);
  float ymax = fmaxf(ay2[0], ay2[1]);
  #pragma unroll
  for (int o = 32; o > 0; o >>= 1){
    ymin = fminf(ymin, __shfl_xor(ymin, o));
    ymax = fmaxf(ymax, __shfl_xor(ymax, o));
  }

  // ---- mask layout detection (per wave; bool8 vs int32 vs float32) ----
  const unsigned int* mw = (const unsigned int*)gmask;
  bool nfb = false, ob = false;
  for (int i = ln; i < (NB_IMG * NGT) / 4; i += 64){
    unsigned int w = mw[i];
    nfb |= (w != 0u && w != 0x3F800000u);
    ob  |= ((w & 0xFFFFFF00u) != 0u);
  }
  const bool byteLayout = __any((int)nfb) && __any((int)ob);

  // ---- per-wave GT y-filter + ordered compaction (own LDS region) ----
  const float4* g4 = (const float4*)gtb;
  float4 g = g4[b * NGT + ln];
  int v = byteLayout ? (gmask[b * NGT + ln] != 0)
                     : (((const unsigned int*)gmask)[b * NGT + ln] != 0u);
  bool pass = v && (g.y < ymax) && (g.w > ymin);   // exact: fail => IoU == 0
  unsigned long long bal = __ballot(pass);
  int pre = __popcll(bal & ((1ull << ln) - 1ull));
  if (pass){
    s_cgt[wv][pre]   = g;
    s_carea[wv][pre] = (g.z - g.x) * (g.w - g.y);
    s_clab[wv][pre]  = gtl[b * NGT + ln];
  }
  int cnt = __popcll(bal);
  float4 g1; bool pass1 = false;
  if (ln < NGT - 64){
    g1 = g4[b * NGT + 64 + ln];
    int v1 = byteLayout ? (gmask[b * NGT + 64 + ln] != 0)
                        : (((const unsigned int*)gmask)[b * NGT + 64 + ln] != 0u);
    pass1 = v1 && (g1.y < ymax) && (g1.w > ymin);
  }
  unsigned long long bal1 = __ballot(pass1);
  int pre1 = cnt + __popcll(bal1 & ((1ull << ln) - 1ull));
  if (pass1){
    s_cgt[wv][pre1]   = g1;
    s_carea[wv][pre1] = (g1.z - g1.x) * (g1.w - g1.y);
    s_clab[wv][pre1]  = gtl[b * NGT + 64 + ln];
  }
  cnt += __popcll(bal1);
  if (ln == 0){
    float4 far4; far4.x = 3e9f; far4.y = 3e9f; far4.z = 3e9f; far4.w = 3e9f;
    s_cgt[wv][cnt]   = far4; s_carea[wv][cnt]   = 0.f; s_clab[wv][cnt]   = 0;
    s_cgt[wv][cnt+1] = far4; s_carea[wv][cnt+1] = 0.f; s_clab[wv][cnt+1] = 0;
  }
  const int cntp = (cnt + 1) & ~1;   // even; 0 if cnt==0

  // ---- IoU argmax + SmoothL1 + pos corr (2 anchors/thread) ----
  float accB = 0.f, posf = 0.f, fcorr = 0.f;
  #pragma unroll
  for (int r = 0; r < 2; ++r){
    int row = r * 256 + tid;
    int a = a0 + row;
    float x1 = ax1[r], y1 = ay1[r], x2 = ax2[r], y2 = ay2[r];
    float areaA = (x2 - x1) * (y2 - y1);
    // division-free argmax (R2-verified): compare I*Ub > Ib*U
    float Ib = -1.f, Ub = 1.f; int best = 0;
    for (int j = 0; j < cntp; j += 2){
      #pragma unroll
      for (int u2 = 0; u2 < 2; ++u2){
        int jj = j + u2;
        float4 gg = s_cgt[wv][jj];
        float lx = fmaxf(x1, gg.x), ly = fmaxf(y1, gg.y);
        float rx = fminf(x2, gg.z), ry = fminf(y2, gg.w);
        float iw = fmaxf(rx - lx, 0.f), ih = fmaxf(ry - ly, 0.f);
        float I  = iw * ih;
        float U  = (areaA + s_carea[wv][jj]) - I;
        bool gt = I * Ub > Ib * U;
        best = gt ? jj : best;
        Ib = gt ? I : Ib;
        Ub = gt ? U : Ub;
      }
    }
    bool va  = a < N_ANCH;
    bool pos = va && (2.f * Ib >= Ub);               // iou >= 0.5
    bool ign = va && !pos && (5.f * Ib >= 2.f * Ub); // 0.4 <= iou < 0.5
    s_wf[row] = ign ? 0.f : 1.f;

    if (pos){
      posf += 1.f;
      float4 gg = s_cgt[wv][best];
      float aw = x2 - x1, ah = y2 - y1;
      float axc = (x1 + x2) * 0.5f, ayc = (y1 + y2) * 0.5f;
      float gw = fmaxf(gg.z - gg.x, 1e-6f), gh = fmaxf(gg.w - gg.y, 1e-6f);
      float gxc = (gg.x + gg.z) * 0.5f, gyc = (gg.y + gg.w) * 0.5f;
      float t0 = (gxc - axc) / aw, t1 = (gyc - ayc) / ah;
      float t2 = LN2 * flog2(gw * frcp(aw));
      float t3 = LN2 * flog2(gh * frcp(ah));
      float4 bp = ((const float4*)bbox)[(size_t)b * N_ANCH + a];
      const float BETA = 1.0f / 9.0f;
      float d0 = fabsf(bp.x - t0), d1 = fabsf(bp.y - t1);
      float d2 = fabsf(bp.z - t2), d3 = fabsf(bp.w - t3);
      accB += (d0 < BETA) ? 4.5f * d0 * d0 : d0 - 0.5f * BETA;
      accB += (d1 < BETA) ? 4.5f * d1 * d1 : d1 - 0.5f * BETA;
      accB += (d2 < BETA) ? 4.5f * d2 * d2 : d2 - 0.5f * BETA;
      accB += (d3 < BETA) ? 4.5f * d3 * d3 : d3 - 0.5f * BETA;
      // (f1 - f0) at the label class (rare scattered dword, issued early)
      int lab = s_clab[wv][best];
      fcorr += corr_term(clsbase[(size_t)row * NC + lab]);
    }
  }
  __syncthreads();

  // ---- lean weighted f0 stream (load + row + 4*f0 + weight-fma) ----
  float fraw = 0.f;
  fraw = fmaf(s_wf[tid / 20],         f0x4(pf0), fraw);            // peeled 0
  fraw = fmaf(s_wf[(tid + 256) / 20], f0x4(pf1), fraw);            // peeled 1
  for (int i = tid + 512; i < nf4; i += 256){
    float4 c4 = cp[i];
    fraw = fmaf(s_wf[i / 20], f0x4(c4), fraw);
  }
  float accC = fmaf(FSCALE, fraw, fcorr);

  // ---- block reduction ----
  #pragma unroll
  for (int o = 32; o > 0; o >>= 1){
    accC += __shfl_down(accC, o);
    accB += __shfl_down(accB, o);
    posf += __shfl_down(posf, o);
  }
  if (ln == 0){ s_r0[wv] = accC; s_r1[wv] = accB; s_r2[wv] = posf; }
  __syncthreads();
  if (tid == 0){
    ws[bid]            = s_r0[0] + s_r0[1] + s_r0[2] + s_r0[3];
    ws[NBLK + bid]     = s_r1[0] + s_r1[1] + s_r1[2] + s_r1[3];
    ws[2 * NBLK + bid] = s_r2[0] + s_r2[1] + s_r2[2] + s_r2[3];
  }
}

__global__ void finalize_kernel(const float* __restrict__ ws,
                                float* __restrict__ out)
{
  __shared__ float sC[NB_IMG], sB[NB_IMG];
  const int tid = threadIdx.x;          // 512 threads = 8 waves
  const int wv = tid >> 6, ln = tid & 63;
  #pragma unroll
  for (int i = 0; i < 2; ++i){
    int b = wv * 2 + i;
    float c = 0.f, bb = 0.f, p = 0.f;
    for (int k = ln; k < BPI; k += 64){
      c  += ws[b * BPI + k];
      bb += ws[NBLK + b * BPI + k];
      p  += ws[2 * NBLK + b * BPI + k];
    }
    #pragma unroll
    for (int o = 32; o > 0; o >>= 1){
      c += __shfl_down(c, o); bb += __shfl_down(bb, o); p += __shfl_down(p, o);
    }
    if (ln == 0){
      float tot = fmaxf(p, 1.f);
      sC[b] = c / tot;
      sB[b] = bb / tot;
    }
  }
  __syncthreads();
  if (tid == 0){
    float lc = 0.f, lb = 0.f;
    #pragma unroll
    for (int b = 0; b < NB_IMG; ++b){ lc += sC[b]; lb += sB[b]; }
    out[0] = lc / 16.f;
    out[1] = 10.f * lb / 16.f;
  }
}

extern "C" void kernel_launch(void* const* d_in, const int* in_sizes, int n_in,
                              void* d_out, int out_size, void* d_ws, size_t ws_size,
                              hipStream_t stream) {
  const float* cls  = (const float*)d_in[0];
  const float* bbox = (const float*)d_in[1];
  const float* gtb  = (const float*)d_in[2];
  const int*   gtl  = (const int*)d_in[3];
  const unsigned char* gmask = (const unsigned char*)d_in[4];

  float* ws = (float*)d_ws;   // 3*NBLK floats, fully overwritten every call

  dim3 grid(BPI, NB_IMG);
  fused_loss_kernel<<<grid, 256, 0, stream>>>(cls, bbox, gtb, gtl, gmask, ws);
  finalize_kernel<<<1, 512, 0, stream>>>(ws, (float*)d_out);
}

// Round 10
// 53.011 us; speedup vs baseline: 1.6883x; 1.0595x over previous
//
#include <hip/hip_runtime.h>

#define N_ANCH 49104
#define NB_IMG 16
#define NGT 100
#define NC 80
#define BPI 96                 // blocks per image
#define APB 512                // anchors (rows) per block
#define NBLK (BPI * NB_IMG)    // 1536
#define ROW_F4 (NC / 4)        // 20 float4 per row
#define MAXG 104               // per-wave filtered GT capacity (100 + sentinels)

#define LOG2E 1.4426950408889634f
#define LN2   0.6931471805599453f
#define FSCALE (0.75f * LN2)

// compile-time f32 half-extents per (ratio,scale) pair k = rr*3 + sc
__constant__ float BW9[9] = {
  (float)(4.0               / 0.7071067811865476 * 0.5),
  (float)(5.039684199579493 / 0.7071067811865476 * 0.5),
  (float)(6.349604207872798 / 0.7071067811865476 * 0.5),
  (float)(4.0               * 0.5),
  (float)(5.039684199579493 * 0.5),
  (float)(6.349604207872798 * 0.5),
  (float)(4.0               / 1.4142135623730951 * 0.5),
  (float)(5.039684199579493 / 1.4142135623730951 * 0.5),
  (float)(6.349604207872798 / 1.4142135623730951 * 0.5),
};
__constant__ float BH9[9] = {
  (float)(4.0               * 0.7071067811865476 * 0.5),
  (float)(5.039684199579493 * 0.7071067811865476 * 0.5),
  (float)(6.349604207872798 * 0.7071067811865476 * 0.5),
  (float)(4.0               * 0.5),
  (float)(5.039684199579493 * 0.5),
  (float)(6.349604207872798 * 0.5),
  (float)(4.0               * 1.4142135623730951 * 0.5),
  (float)(5.039684199579493 * 1.4142135623730951 * 0.5),
  (float)(6.349604207872798 * 1.4142135623730951 * 0.5),
};

__device__ __forceinline__ float frcp(float x){ return __builtin_amdgcn_rcpf(x); }
__device__ __forceinline__ float fexp2(float x){ return __builtin_amdgcn_exp2f(x); }
__device__ __forceinline__ float flog2(float x){ return __builtin_amdgcn_logf(x); }

// p(x)^2 * softplus(x)/LN2  (caller scales by 0.75*LN2)
__device__ __forceinline__ float f0_term(float x){
  float xl = x * LOG2E;
  float mx = fmaxf(xl, 0.f);
  float mn = fminf(xl, 0.f);
  float u  = fexp2(mn - mx);      // e^{-|x|}
  float w  = 1.0f + u;
  float lw = flog2(w);
  float g  = mn - lw;             // log2(sigmoid)
  return fexp2(g + g) * (lw + mx);
}
__device__ __forceinline__ float f0x4(float4 c4){
  return (f0_term(c4.x) + f0_term(c4.y)) + (f0_term(c4.z) + f0_term(c4.w));
}

// (f1 - f0) correction for the one-hot label class (absolute units)
__device__ __forceinline__ float corr_term(float x){
  float xl = x * LOG2E;
  float mx = fmaxf(xl, 0.f);
  float mn = fminf(xl, 0.f);
  float u  = fexp2(mn - mx);
  float w  = 1.0f + u;
  float lw = flog2(w);
  float p2   = fexp2(2.f * (mn - lw));
  float omp2 = fexp2(-2.f * (mx + lw));
  float sp   = LN2 * (lw + mx);
  float spn  = LN2 * (lw - mn);
  return 0.25f * omp2 * spn - 0.75f * p2 * sp;
}

// f32 anchor geometry (table-based, no f64, no divides)
__device__ __forceinline__ void anchor_geom(int a, float& x1, float& y1,
                                            float& x2, float& y2){
  int lg, st, rel;
  if      (a < 36864){ lg = 6; st = 8;   rel = a; }
  else if (a < 46080){ lg = 5; st = 16;  rel = a - 36864; }
  else if (a < 48384){ lg = 4; st = 32;  rel = a - 46080; }
  else if (a < 48960){ lg = 3; st = 64;  rel = a - 48384; }
  else               { lg = 2; st = 128; rel = a - 48960; }
  int cell = rel / 9;
  int k    = rel - cell * 9;
  int yy   = cell >> lg;
  int xx   = cell & ((1 << lg) - 1);
  float stf = (float)st;
  float cx = ((float)xx + 0.5f) * stf;   // exact in f32
  float cy = ((float)yy + 0.5f) * stf;
  float w2 = stf * BW9[k];               // exact scaling of correctly-rounded base
  float h2 = stf * BH9[k];
  x1 = cx - w2; y1 = cy - h2; x2 = cx + w2; y2 = cy + h2;
}

__global__ __launch_bounds__(256, 6) void fused_loss_kernel(
    const float* __restrict__ cls,
    const float* __restrict__ bbox,
    const float* __restrict__ gtb,
    const int*   __restrict__ gtl,
    const unsigned char* __restrict__ gmask,
    float* __restrict__ ws)
{
  const int tid = threadIdx.x;
  const int wv = tid >> 6, ln = tid & 63;
  const int b  = blockIdx.y;
  const int a0 = blockIdx.x * APB;
  const int bid = b * BPI + blockIdx.x;
  const int nvalid = min(N_ANCH - a0, APB);
  const int nf4 = nvalid * ROW_F4;       // >= 9280 always

  __shared__ float4 s_cgt[4][MAXG];
  __shared__ float  s_carea[4][MAXG];
  __shared__ int    s_clab[4][MAXG];
  __shared__ float  s_wf[APB];           // 1 = counted (pos|neg), 0 = ignored
  __shared__ float  s_r0[4], s_r1[4], s_r2[4];

  const float* clsbase = cls + (size_t)(b * N_ANCH + a0) * NC;
  const float4* cp = (const float4*)clsbase;

  // ---- prefetch first 4 stream iterations (issued at cycle ~0; keeps HBM
  //      busy through the lockstep prelude — 1536 blocks = exactly 1 round) ----
  float4 pf0 = cp[tid];
  float4 pf1 = cp[tid + 256];
  float4 pf2 = cp[tid + 512];
  float4 pf3 = cp[tid + 768];

  // ---- f32 geometry for this thread's 2 anchors ----
  float ax1[2], ay1[2], ax2[2], ay2[2];
  #pragma unroll
  for (int r = 0; r < 2; ++r){
    int a = a0 + r * 256 + tid;
    if (a < N_ANCH) anchor_geom(a, ax1[r], ay1[r], ax2[r], ay2[r]);
    else { ax1[r] = 0.f; ay1[r] = 3.0e38f; ax2[r] = 0.f; ay2[r] = -3.0e38f; }
  }

  // ---- per-wave y-extent (no LDS, no barrier) ----
  float ymin = fminf(ay1[0], ay1[1]);
  float ymax = fmaxf(ay2[0], ay2[1]);
  #pragma unroll
  for (int o = 32; o > 0; o >>= 1){
    ymin = fminf(ymin, __shfl_xor(ymin, o));
    ymax = fmaxf(ymax, __shfl_xor(ymax, o));
  }

  // ---- mask layout detection (per wave; bool8 vs int32 vs float32) ----
  const unsigned int* mw = (const unsigned int*)gmask;
  bool nfb = false, ob = false;
  for (int i = ln; i < (NB_IMG * NGT) / 4; i += 64){
    unsigned int w = mw[i];
    nfb |= (w != 0u && w != 0x3F800000u);
    ob  |= ((w & 0xFFFFFF00u) != 0u);
  }
  const bool byteLayout = __any((int)nfb) && __any((int)ob);

  // ---- per-wave GT y-filter + ordered compaction (own LDS region) ----
  const float4* g4 = (const float4*)gtb;
  float4 g = g4[b * NGT + ln];
  int v = byteLayout ? (gmask[b * NGT + ln] != 0)
                     : (((const unsigned int*)gmask)[b * NGT + ln] != 0u);
  bool pass = v && (g.y < ymax) && (g.w > ymin);   // exact: fail => IoU == 0
  unsigned long long bal = __ballot(pass);
  int pre = __popcll(bal & ((1ull << ln) - 1ull));
  if (pass){
    s_cgt[wv][pre]   = g;
    s_carea[wv][pre] = (g.z - g.x) * (g.w - g.y);
    s_clab[wv][pre]  = gtl[b * NGT + ln];
  }
  int cnt = __popcll(bal);
  float4 g1; bool pass1 = false;
  if (ln < NGT - 64){
    g1 = g4[b * NGT + 64 + ln];
    int v1 = byteLayout ? (gmask[b * NGT + 64 + ln] != 0)
                        : (((const unsigned int*)gmask)[b * NGT + 64 + ln] != 0u);
    pass1 = v1 && (g1.y < ymax) && (g1.w > ymin);
  }
  unsigned long long bal1 = __ballot(pass1);
  int pre1 = cnt + __popcll(bal1 & ((1ull << ln) - 1ull));
  if (pass1){
    s_cgt[wv][pre1]   = g1;
    s_carea[wv][pre1] = (g1.z - g1.x) * (g1.w - g1.y);
    s_clab[wv][pre1]  = gtl[b * NGT + 64 + ln];
  }
  cnt += __popcll(bal1);
  if (ln == 0){
    float4 far4; far4.x = 3e9f; far4.y = 3e9f; far4.z = 3e9f; far4.w = 3e9f;
    s_cgt[wv][cnt]   = far4; s_carea[wv][cnt]   = 0.f; s_clab[wv][cnt]   = 0;
    s_cgt[wv][cnt+1] = far4; s_carea[wv][cnt+1] = 0.f; s_clab[wv][cnt+1] = 0;
  }
  const int cntp = (cnt + 1) & ~1;   // even; 0 if cnt==0

  // ---- IoU argmax + SmoothL1 + pos corr (2 anchors/thread) ----
  float accB = 0.f, posf = 0.f, fcorr = 0.f;
  #pragma unroll
  for (int r = 0; r < 2; ++r){
    int row = r * 256 + tid;
    int a = a0 + row;
    float x1 = ax1[r], y1 = ay1[r], x2 = ax2[r], y2 = ay2[r];
    float areaA = (x2 - x1) * (y2 - y1);
    // division-free argmax (R2-verified): compare I*Ub > Ib*U
    float Ib = -1.f, Ub = 1.f; int best = 0;
    for (int j = 0; j < cntp; j += 2){
      #pragma unroll
      for (int u2 = 0; u2 < 2; ++u2){
        int jj = j + u2;
        float4 gg = s_cgt[wv][jj];
        float lx = fmaxf(x1, gg.x), ly = fmaxf(y1, gg.y);
        float rx = fminf(x2, gg.z), ry = fminf(y2, gg.w);
        float iw = fmaxf(rx - lx, 0.f), ih = fmaxf(ry - ly, 0.f);
        float I  = iw * ih;
        float U  = (areaA + s_carea[wv][jj]) - I;
        bool gt = I * Ub > Ib * U;
        best = gt ? jj : best;
        Ib = gt ? I : Ib;
        Ub = gt ? U : Ub;
      }
    }
    bool va  = a < N_ANCH;
    bool pos = va && (2.f * Ib >= Ub);               // iou >= 0.5
    bool ign = va && !pos && (5.f * Ib >= 2.f * Ub); // 0.4 <= iou < 0.5
    s_wf[row] = ign ? 0.f : 1.f;

    if (pos){
      posf += 1.f;
      float4 gg = s_cgt[wv][best];
      float aw = x2 - x1, ah = y2 - y1;
      float axc = (x1 + x2) * 0.5f, ayc = (y1 + y2) * 0.5f;
      float gw = fmaxf(gg.z - gg.x, 1e-6f), gh = fmaxf(gg.w - gg.y, 1e-6f);
      float gxc = (gg.x + gg.z) * 0.5f, gyc = (gg.y + gg.w) * 0.5f;
      float t0 = (gxc - axc) / aw, t1 = (gyc - ayc) / ah;
      float t2 = LN2 * flog2(gw * frcp(aw));
      float t3 = LN2 * flog2(gh * frcp(ah));
      float4 bp = ((const float4*)bbox)[(size_t)b * N_ANCH + a];
      const float BETA = 1.0f / 9.0f;
      float d0 = fabsf(bp.x - t0), d1 = fabsf(bp.y - t1);
      float d2 = fabsf(bp.z - t2), d3 = fabsf(bp.w - t3);
      accB += (d0 < BETA) ? 4.5f * d0 * d0 : d0 - 0.5f * BETA;
      accB += (d1 < BETA) ? 4.5f * d1 * d1 : d1 - 0.5f * BETA;
      accB += (d2 < BETA) ? 4.5f * d2 * d2 : d2 - 0.5f * BETA;
      accB += (d3 < BETA) ? 4.5f * d3 * d3 : d3 - 0.5f * BETA;
      // (f1 - f0) at the label class (rare scattered dword)
      int lab = s_clab[wv][best];
      fcorr += corr_term(clsbase[(size_t)row * NC + lab]);
    }
  }
  __syncthreads();

  // ---- weighted f0 stream: 4-wide, 4 loads in flight, indep accumulators ----
  float fr0 = 0.f, fr1 = 0.f, fr2 = 0.f, fr3 = 0.f;
  fr0 = fmaf(s_wf[tid / 20],         f0x4(pf0), fr0);
  fr1 = fmaf(s_wf[(tid + 256) / 20], f0x4(pf1), fr1);
  fr2 = fmaf(s_wf[(tid + 512) / 20], f0x4(pf2), fr2);
  fr3 = fmaf(s_wf[(tid + 768) / 20], f0x4(pf3), fr3);
  int i = tid + 1024;
  for (; i + 768 < nf4; i += 1024){
    float4 c0 = cp[i];
    float4 c1 = cp[i + 256];
    float4 c2 = cp[i + 512];
    float4 c3 = cp[i + 768];
    fr0 = fmaf(s_wf[i / 20],         f0x4(c0), fr0);
    fr1 = fmaf(s_wf[(i + 256) / 20], f0x4(c1), fr1);
    fr2 = fmaf(s_wf[(i + 512) / 20], f0x4(c2), fr2);
    fr3 = fmaf(s_wf[(i + 768) / 20], f0x4(c3), fr3);
  }
  for (; i < nf4; i += 256){
    float4 c4 = cp[i];
    fr0 = fmaf(s_wf[i / 20], f0x4(c4), fr0);
  }
  float accC = fmaf(FSCALE, (fr0 + fr1) + (fr2 + fr3), fcorr);

  // ---- block reduction ----
  #pragma unroll
  for (int o = 32; o > 0; o >>= 1){
    accC += __shfl_down(accC, o);
    accB += __shfl_down(accB, o);
    posf += __shfl_down(posf, o);
  }
  if (ln == 0){ s_r0[wv] = accC; s_r1[wv] = accB; s_r2[wv] = posf; }
  __syncthreads();
  if (tid == 0){
    ws[bid]            = s_r0[0] + s_r0[1] + s_r0[2] + s_r0[3];
    ws[NBLK + bid]     = s_r1[0] + s_r1[1] + s_r1[2] + s_r1[3];
    ws[2 * NBLK + bid] = s_r2[0] + s_r2[1] + s_r2[2] + s_r2[3];
  }
}

__global__ void finalize_kernel(const float* __restrict__ ws,
                                float* __restrict__ out)
{
  __shared__ float sC[NB_IMG], sB[NB_IMG];
  const int tid = threadIdx.x;          // 512 threads = 8 waves
  const int wv = tid >> 6, ln = tid & 63;
  #pragma unroll
  for (int i = 0; i < 2; ++i){
    int b = wv * 2 + i;
    float c = 0.f, bb = 0.f, p = 0.f;
    for (int k = ln; k < BPI; k += 64){
      c  += ws[b * BPI + k];
      bb += ws[NBLK + b * BPI + k];
      p  += ws[2 * NBLK + b * BPI + k];
    }
    #pragma unroll
    for (int o = 32; o > 0; o >>= 1){
      c += __shfl_down(c, o); bb += __shfl_down(bb, o); p += __shfl_down(p, o);
    }
    if (ln == 0){
      float tot = fmaxf(p, 1.f);
      sC[b] = c / tot;
      sB[b] = bb / tot;
    }
  }
  __syncthreads();
  if (tid == 0){
    float lc = 0.f, lb = 0.f;
    #pragma unroll
    for (int b = 0; b < NB_IMG; ++b){ lc += sC[b]; lb += sB[b]; }
    out[0] = lc / 16.f;
    out[1] = 10.f * lb / 16.f;
  }
}

extern "C" void kernel_launch(void* const* d_in, const int* in_sizes, int n_in,
                              void* d_out, int out_size, void* d_ws, size_t ws_size,
                              hipStream_t stream) {
  const float* cls  = (const float*)d_in[0];
  const float* bbox = (const float*)d_in[1];
  const float* gtb  = (const float*)d_in[2];
  const int*   gtl  = (const int*)d_in[3];
  const unsigned char* gmask = (const unsigned char*)d_in[4];

  float* ws = (float*)d_ws;   // 3*NBLK floats, fully overwritten every call

  dim3 grid(BPI, NB_IMG);
  fused_loss_kernel<<<grid, 256, 0, stream>>>(cls, bbox, gtb, gtl, gmask, ws);
  finalize_kernel<<<1, 512, 0, stream>>>(ws, (float*)d_out);
}

// Round 11
// 52.882 us; speedup vs baseline: 1.6924x; 1.0025x over previous
//
#include <hip/hip_runtime.h>

#define N_ANCH 49104
#define NB_IMG 16
#define NGT 100
#define NC 80
#define BPI 96                 // blocks per image
#define APB 512                // anchors (rows) per block
#define RPW 128                // rows per wave
#define NBLK (BPI * NB_IMG)    // 1536
#define ROW_F4 (NC / 4)        // 20 float4 per row
#define WCH (RPW * ROW_F4)     // 2560 float4 per wave chunk
#define MAXG 104               // per-wave filtered GT capacity
#define NPF 6                  // prefetch depth (float4 per lane)

#define LOG2E 1.4426950408889634f
#define LN2   0.6931471805599453f
#define FSCALE (0.75f * LN2)

// compile-time f32 half-extents per (ratio,scale) pair k = rr*3 + sc
__constant__ float BW9[9] = {
  (float)(4.0               / 0.7071067811865476 * 0.5),
  (float)(5.039684199579493 / 0.7071067811865476 * 0.5),
  (float)(6.349604207872798 / 0.7071067811865476 * 0.5),
  (float)(4.0               * 0.5),
  (float)(5.039684199579493 * 0.5),
  (float)(6.349604207872798 * 0.5),
  (float)(4.0               / 1.4142135623730951 * 0.5),
  (float)(5.039684199579493 / 1.4142135623730951 * 0.5),
  (float)(6.349604207872798 / 1.4142135623730951 * 0.5),
};
__constant__ float BH9[9] = {
  (float)(4.0               * 0.7071067811865476 * 0.5),
  (float)(5.039684199579493 * 0.7071067811865476 * 0.5),
  (float)(6.349604207872798 * 0.7071067811865476 * 0.5),
  (float)(4.0               * 0.5),
  (float)(5.039684199579493 * 0.5),
  (float)(6.349604207872798 * 0.5),
  (float)(4.0               * 1.4142135623730951 * 0.5),
  (float)(5.039684199579493 * 1.4142135623730951 * 0.5),
  (float)(6.349604207872798 * 1.4142135623730951 * 0.5),
};

__device__ __forceinline__ float frcp(float x){ return __builtin_amdgcn_rcpf(x); }
__device__ __forceinline__ float fexp2(float x){ return __builtin_amdgcn_exp2f(x); }
__device__ __forceinline__ float flog2(float x){ return __builtin_amdgcn_logf(x); }

// p(x)^2 * softplus(x)/LN2  (caller scales by 0.75*LN2)
__device__ __forceinline__ float f0_term(float x){
  float xl = x * LOG2E;
  float mx = fmaxf(xl, 0.f);
  float mn = fminf(xl, 0.f);
  float u  = fexp2(mn - mx);      // e^{-|x|}
  float w  = 1.0f + u;
  float lw = flog2(w);
  float g  = mn - lw;             // log2(sigmoid)
  return fexp2(g + g) * (lw + mx);
}
__device__ __forceinline__ float f0x4(float4 c4){
  return (f0_term(c4.x) + f0_term(c4.y)) + (f0_term(c4.z) + f0_term(c4.w));
}

// (f1 - f0) correction for the one-hot label class (absolute units)
__device__ __forceinline__ float corr_term(float x){
  float xl = x * LOG2E;
  float mx = fmaxf(xl, 0.f);
  float mn = fminf(xl, 0.f);
  float u  = fexp2(mn - mx);
  float w  = 1.0f + u;
  float lw = flog2(w);
  float p2   = fexp2(2.f * (mn - lw));
  float omp2 = fexp2(-2.f * (mx + lw));
  float sp   = LN2 * (lw + mx);
  float spn  = LN2 * (lw - mn);
  return 0.25f * omp2 * spn - 0.75f * p2 * sp;
}

// f32 anchor geometry (table-based, no f64, no divides)
__device__ __forceinline__ void anchor_geom(int a, float& x1, float& y1,
                                            float& x2, float& y2){
  int lg, st, rel;
  if      (a < 36864){ lg = 6; st = 8;   rel = a; }
  else if (a < 46080){ lg = 5; st = 16;  rel = a - 36864; }
  else if (a < 48384){ lg = 4; st = 32;  rel = a - 46080; }
  else if (a < 48960){ lg = 3; st = 64;  rel = a - 48384; }
  else               { lg = 2; st = 128; rel = a - 48960; }
  int cell = rel / 9;
  int k    = rel - cell * 9;
  int yy   = cell >> lg;
  int xx   = cell & ((1 << lg) - 1);
  float stf = (float)st;
  float cx = ((float)xx + 0.5f) * stf;   // exact in f32
  float cy = ((float)yy + 0.5f) * stf;
  float w2 = stf * BW9[k];               // exact scaling of correctly-rounded base
  float h2 = stf * BH9[k];
  x1 = cx - w2; y1 = cy - h2; x2 = cx + w2; y2 = cy + h2;
}

__global__ __launch_bounds__(256, 6) void fused_loss_kernel(
    const float* __restrict__ cls,
    const float* __restrict__ bbox,
    const float* __restrict__ gtb,
    const int*   __restrict__ gtl,
    const unsigned char* __restrict__ gmask,
    float* __restrict__ ws)
{
  const int tid = threadIdx.x;
  const int wv = tid >> 6, ln = tid & 63;
  const int b  = blockIdx.y;
  const int a0 = blockIdx.x * APB;
  const int bid = b * BPI + blockIdx.x;
  const int nvalid = min(N_ANCH - a0, APB);
  const int nf4 = nvalid * ROW_F4;
  const int wb  = wv * WCH;                       // wave chunk base (float4)
  const int jend = min(WCH, nf4 - wb);            // >= 1600 always
  const int rbase = wv * RPW;                     // wave's first block-row

  __shared__ float4 s_cgt[4][MAXG];
  __shared__ float  s_carea[4][MAXG];
  __shared__ int    s_clab[4][MAXG];
  __shared__ float  s_wf[APB];     // row weight; wave-private slices, no barrier
  __shared__ float  s_r0[4], s_r1[4], s_r2[4];

  const float* clsbase = cls + (size_t)(b * N_ANCH + a0) * NC;
  const float4* cp = (const float4*)clsbase;

  // ---- prefetch first NPF stream iterations of THIS WAVE's chunk (t ~ 0) ----
  float4 pf[NPF];
  #pragma unroll
  for (int k = 0; k < NPF; ++k) pf[k] = cp[wb + ln + k * 64];   // 384 < 1600 safe

  // ---- f32 geometry for this lane's 2 rows (wave-owned rows) ----
  float ax1[2], ay1[2], ax2[2], ay2[2];
  #pragma unroll
  for (int r = 0; r < 2; ++r){
    int a = a0 + rbase + 2 * ln + r;
    if (a < N_ANCH) anchor_geom(a, ax1[r], ay1[r], ax2[r], ay2[r]);
    else { ax1[r] = 0.f; ay1[r] = 3.0e38f; ax2[r] = 0.f; ay2[r] = -3.0e38f; }
  }

  // ---- per-wave y-extent over its own 128 rows (tight; no LDS/barrier) ----
  float ymin = fminf(ay1[0], ay1[1]);
  float ymax = fmaxf(ay2[0], ay2[1]);
  #pragma unroll
  for (int o = 32; o > 0; o >>= 1){
    ymin = fminf(ymin, __shfl_xor(ymin, o));
    ymax = fmaxf(ymax, __shfl_xor(ymax, o));
  }

  // ---- mask layout detection (per wave; bool8 vs int32 vs float32) ----
  const unsigned int* mw = (const unsigned int*)gmask;
  bool nfb = false, ob = false;
  for (int i = ln; i < (NB_IMG * NGT) / 4; i += 64){
    unsigned int w = mw[i];
    nfb |= (w != 0u && w != 0x3F800000u);
    ob  |= ((w & 0xFFFFFF00u) != 0u);
  }
  const bool byteLayout = __any((int)nfb) && __any((int)ob);

  // ---- per-wave GT y-filter + ordered compaction (own LDS region) ----
  const float4* g4 = (const float4*)gtb;
  float4 g = g4[b * NGT + ln];
  int v = byteLayout ? (gmask[b * NGT + ln] != 0)
                     : (((const unsigned int*)gmask)[b * NGT + ln] != 0u);
  bool pass = v && (g.y < ymax) && (g.w > ymin);   // exact: fail => IoU == 0
  unsigned long long bal = __ballot(pass);
  int pre = __popcll(bal & ((1ull << ln) - 1ull));
  if (pass){
    s_cgt[wv][pre]   = g;
    s_carea[wv][pre] = (g.z - g.x) * (g.w - g.y);
    s_clab[wv][pre]  = gtl[b * NGT + ln];
  }
  int cnt = __popcll(bal);
  float4 g1; bool pass1 = false;
  if (ln < NGT - 64){
    g1 = g4[b * NGT + 64 + ln];
    int v1 = byteLayout ? (gmask[b * NGT + 64 + ln] != 0)
                        : (((const unsigned int*)gmask)[b * NGT + 64 + ln] != 0u);
    pass1 = v1 && (g1.y < ymax) && (g1.w > ymin);
  }
  unsigned long long bal1 = __ballot(pass1);
  int pre1 = cnt + __popcll(bal1 & ((1ull << ln) - 1ull));
  if (pass1){
    s_cgt[wv][pre1]   = g1;
    s_carea[wv][pre1] = (g1.z - g1.x) * (g1.w - g1.y);
    s_clab[wv][pre1]  = gtl[b * NGT + 64 + ln];
  }
  cnt += __popcll(bal1);
  if (ln == 0){
    float4 far4; far4.x = 3e9f; far4.y = 3e9f; far4.z = 3e9f; far4.w = 3e9f;
    s_cgt[wv][cnt]   = far4; s_carea[wv][cnt]   = 0.f; s_clab[wv][cnt]   = 0;
    s_cgt[wv][cnt+1] = far4; s_carea[wv][cnt+1] = 0.f; s_clab[wv][cnt+1] = 0;
  }
  const int cntp = (cnt + 1) & ~1;   // even; 0 if cnt==0

  // ---- IoU argmax + SmoothL1 + pos corr for this lane's 2 rows ----
  float accB = 0.f, posf = 0.f, fcorr = 0.f;
  #pragma unroll
  for (int r = 0; r < 2; ++r){
    int row = rbase + 2 * ln + r;
    int a = a0 + row;
    float x1 = ax1[r], y1 = ay1[r], x2 = ax2[r], y2 = ay2[r];
    float areaA = (x2 - x1) * (y2 - y1);
    // division-free argmax (R2-verified): compare I*Ub > Ib*U
    float Ib = -1.f, Ub = 1.f; int best = 0;
    for (int j = 0; j < cntp; j += 2){
      #pragma unroll
      for (int u2 = 0; u2 < 2; ++u2){
        int jj = j + u2;
        float4 gg = s_cgt[wv][jj];
        float lx = fmaxf(x1, gg.x), ly = fmaxf(y1, gg.y);
        float rx = fminf(x2, gg.z), ry = fminf(y2, gg.w);
        float iw = fmaxf(rx - lx, 0.f), ih = fmaxf(ry - ly, 0.f);
        float I  = iw * ih;
        float U  = (areaA + s_carea[wv][jj]) - I;
        bool gt = I * Ub > Ib * U;
        best = gt ? jj : best;
        Ib = gt ? I : Ib;
        Ub = gt ? U : Ub;
      }
    }
    bool va  = a < N_ANCH;
    bool pos = va && (2.f * Ib >= Ub);               // iou >= 0.5
    bool ign = va && !pos && (5.f * Ib >= 2.f * Ub); // 0.4 <= iou < 0.5
    s_wf[row] = ign ? 0.f : 1.f;                     // wave-private slice

    if (pos){
      posf += 1.f;
      float4 gg = s_cgt[wv][best];
      float aw = x2 - x1, ah = y2 - y1;
      float axc = (x1 + x2) * 0.5f, ayc = (y1 + y2) * 0.5f;
      float gw = fmaxf(gg.z - gg.x, 1e-6f), gh = fmaxf(gg.w - gg.y, 1e-6f);
      float gxc = (gg.x + gg.z) * 0.5f, gyc = (gg.y + gg.w) * 0.5f;
      float t0 = (gxc - axc) / aw, t1 = (gyc - ayc) / ah;
      float t2 = LN2 * flog2(gw * frcp(aw));
      float t3 = LN2 * flog2(gh * frcp(ah));
      float4 bp = ((const float4*)bbox)[(size_t)b * N_ANCH + a];
      const float BETA = 1.0f / 9.0f;
      float d0 = fabsf(bp.x - t0), d1 = fabsf(bp.y - t1);
      float d2 = fabsf(bp.z - t2), d3 = fabsf(bp.w - t3);
      accB += (d0 < BETA) ? 4.5f * d0 * d0 : d0 - 0.5f * BETA;
      accB += (d1 < BETA) ? 4.5f * d1 * d1 : d1 - 0.5f * BETA;
      accB += (d2 < BETA) ? 4.5f * d2 * d2 : d2 - 0.5f * BETA;
      accB += (d3 < BETA) ? 4.5f * d3 * d3 : d3 - 0.5f * BETA;
      // (f1 - f0) at the label class (rare scattered dword)
      int lab = s_clab[wv][best];
      fcorr += corr_term(clsbase[(size_t)row * NC + lab]);
    }
  }
  // no __syncthreads: this wave reads only its own s_wf slice (LDS is
  // in-order within a wave; indices are opaque so compiler keeps order)

  // ---- weighted f0 stream over THIS WAVE's contiguous chunk ----
  float fr0 = 0.f, fr1 = 0.f, fr2 = 0.f, fr3 = 0.f;
  #pragma unroll
  for (int k = 0; k < NPF; ++k){
    int j = ln + k * 64;
    float t = fmaf(s_wf[rbase + j / 20], f0x4(pf[k]), 0.f);
    if ((k & 3) == 0) fr0 += t; else if ((k & 3) == 1) fr1 += t;
    else if ((k & 3) == 2) fr2 += t; else fr3 += t;
  }
  int j = NPF * 64 + ln;
  for (; j + 192 < jend; j += 256){
    float4 c0 = cp[wb + j];
    float4 c1 = cp[wb + j + 64];
    float4 c2 = cp[wb + j + 128];
    float4 c3 = cp[wb + j + 192];
    fr0 = fmaf(s_wf[rbase + j / 20],         f0x4(c0), fr0);
    fr1 = fmaf(s_wf[rbase + (j + 64) / 20],  f0x4(c1), fr1);
    fr2 = fmaf(s_wf[rbase + (j + 128) / 20], f0x4(c2), fr2);
    fr3 = fmaf(s_wf[rbase + (j + 192) / 20], f0x4(c3), fr3);
  }
  for (; j < jend; j += 64){
    float4 c4 = cp[wb + j];
    fr0 = fmaf(s_wf[rbase + j / 20], f0x4(c4), fr0);
  }
  float accC = fmaf(FSCALE, (fr0 + fr1) + (fr2 + fr3), fcorr);

  // ---- block reduction (single barrier of the kernel) ----
  #pragma unroll
  for (int o = 32; o > 0; o >>= 1){
    accC += __shfl_down(accC, o);
    accB += __shfl_down(accB, o);
    posf += __shfl_down(posf, o);
  }
  if (ln == 0){ s_r0[wv] = accC; s_r1[wv] = accB; s_r2[wv] = posf; }
  __syncthreads();
  if (tid == 0){
    ws[bid]            = s_r0[0] + s_r0[1] + s_r0[2] + s_r0[3];
    ws[NBLK + bid]     = s_r1[0] + s_r1[1] + s_r1[2] + s_r1[3];
    ws[2 * NBLK + bid] = s_r2[0] + s_r2[1] + s_r2[2] + s_r2[3];
  }
}

__global__ void finalize_kernel(const float* __restrict__ ws,
                                float* __restrict__ out)
{
  __shared__ float sC[NB_IMG], sB[NB_IMG];
  const int tid = threadIdx.x;          // 512 threads = 8 waves
  const int wv = tid >> 6, ln = tid & 63;
  #pragma unroll
  for (int i = 0; i < 2; ++i){
    int b = wv * 2 + i;
    float c = 0.f, bb = 0.f, p = 0.f;
    for (int k = ln; k < BPI; k += 64){
      c  += ws[b * BPI + k];
      bb += ws[NBLK + b * BPI + k];
      p  += ws[2 * NBLK + b * BPI + k];
    }
    #pragma unroll
    for (int o = 32; o > 0; o >>= 1){
      c += __shfl_down(c, o); bb += __shfl_down(bb, o); p += __shfl_down(p, o);
    }
    if (ln == 0){
      float tot = fmaxf(p, 1.f);
      sC[b] = c / tot;
      sB[b] = bb / tot;
    }
  }
  __syncthreads();
  if (tid == 0){
    float lc = 0.f, lb = 0.f;
    #pragma unroll
    for (int b = 0; b < NB_IMG; ++b){ lc += sC[b]; lb += sB[b]; }
    out[0] = lc / 16.f;
    out[1] = 10.f * lb / 16.f;
  }
}

extern "C" void kernel_launch(void* const* d_in, const int* in_sizes, int n_in,
                              void* d_out, int out_size, void* d_ws, size_t ws_size,
                              hipStream_t stream) {
  const float* cls  = (const float*)d_in[0];
  const float* bbox = (const float*)d_in[1];
  const float* gtb  = (const float*)d_in[2];
  const int*   gtl  = (const int*)d_in[3];
  const unsigned char* gmask = (const unsigned char*)d_in[4];

  float* ws = (float*)d_ws;   // 3*NBLK floats, fully overwritten every call

  dim3 grid(BPI, NB_IMG);
  fused_loss_kernel<<<grid, 256, 0, stream>>>(cls, bbox, gtb, gtl, gmask, ws);
  finalize_kernel<<<1, 512, 0, stream>>>(ws, (float*)d_out);
}